// Round 5
// baseline (290.960 us; speedup 1.0000x reference)
//
#include <hip/hip_runtime.h>

// Topo_Attention: out[b,c,t] = softmax_c( sum_l w[l]*tanh(sum_m v[l,m]*h_c[b,t,m]) )
// B=32, T=4096, M=256, L=128.  bf16 MFMA GEMM; memory-bound.
// R9: R4 skeleton (the only clean-compiling structure) at DOUBLE the waves/CU.
//     R4 vs R8 showed per-wave DMA throughput is invariant (~0.5 B/cyc/wave)
//     regardless of step size or in-flight depth -> the kernel is per-wave
//     rate-limited, so the lever is wave count. V must live in LDS (64KB), so
//     16 waves/CU comes from ONE 1024-thread WG per CU: LDS = 64KB V +
//     16 waves x 3 slots x 2KB = 160KB (full pool, AITER fmha precedent).
//     Per-wave step identical to R4 (2KB, depth-2 prefetch, vmcnt 4/2/0).
//     Numerics bit-identical to R1-R8.

typedef unsigned short u16;
typedef unsigned int   u32;
typedef __bf16 bf16x8 __attribute__((ext_vector_type(8)));
typedef float  f32x4  __attribute__((ext_vector_type(4)));

union ABFrag { bf16x8 v; u16 u[8]; uint4 q4; };

__device__ __forceinline__ u16 f2bf(float f) {
  // round-to-nearest-even fp32 -> bf16 (finite inputs; no NaN path)
  u32 u = __float_as_uint(f);
  u += 0x7fffu + ((u >> 16) & 1u);
  return (u16)(u >> 16);
}

__device__ __forceinline__ float fast_tanh(float x) {
  float t = __builtin_amdgcn_exp2f(2.885390082f * x);
  return 1.0f - 2.0f * __builtin_amdgcn_rcpf(t + 1.0f);
}

typedef const __attribute__((address_space(1))) void gvoid;
typedef __attribute__((address_space(3))) void lvoid;

__device__ __forceinline__ void dma16(const char* g, char* l) {
  __builtin_amdgcn_global_load_lds((gvoid*)g, (lvoid*)l, 16, 0, 0);
}

#define NWG    256
#define NWAVES 16
#define ITERS  4
#define TOT    (ITERS * 8)                    // 32 ks-steps
#define ROWS_PER_IT (NWG * NWAVES * 8)        // 32768 t-rows per iter
#define ITSTR  ((size_t)ROWS_PER_IT * 1024)   // per-iter global byte stride
#define SMEMSZ (65536 + NWAVES * 3 * 2048)    // V 64KB + 16 waves x 3 x 2KB = 160KB

__global__ __launch_bounds__(1024, 1) void topo_attn_kernel(
    const float* __restrict__ h1, const float* __restrict__ h2,
    const float* __restrict__ w,  const float* __restrict__ vfp,
    float* __restrict__ out) {
  extern __shared__ __align__(16) char smem[];
  u16*  vlds   = (u16*)smem;                 // V bf16, R1 rotate layout (64KB)
  char* albase = smem + 65536;               // A staging (96KB)

  const int tid = threadIdx.x;

  { // one-time: convert V fp32 -> bf16 into LDS, rotate swizzle (chunk g -> (g+l)&31)
    const float4* src = (const float4*)vfp;
    #pragma unroll
    for (int k = 0; k < 4; ++k) {
      int gi = k * 1024 + tid;           // 8-elem group index, 0..4095
      float4 f0 = src[gi * 2];
      float4 f1 = src[gi * 2 + 1];
      ABFrag t;
      t.u[0] = f2bf(f0.x); t.u[1] = f2bf(f0.y); t.u[2] = f2bf(f0.z); t.u[3] = f2bf(f0.w);
      t.u[4] = f2bf(f1.x); t.u[5] = f2bf(f1.y); t.u[6] = f2bf(f1.z); t.u[7] = f2bf(f1.w);
      int l = gi >> 5;                   // 0..127
      int g = gi & 31;                   // 0..31
      *(uint4*)&vlds[(l << 8) + (((g + l) & 31) << 3)] = t.q4;
    }
  }
  __syncthreads();                       // only barrier in the kernel

  const int lane = tid & 63;
  const int wave = tid >> 6;             // 0..15
  const int l15  = lane & 15;            // MFMA A-row / D-col lane index
  const int q    = lane >> 4;            // quad: A k = q*8+j ; D row = q*4+reg

  float wreg[8];
  #pragma unroll
  for (int lt = 0; lt < 8; ++lt) wreg[lt] = w[lt * 16 + l15];

  char* aslot = albase + wave * 6144;    // 3 slots x 2048B, wave-private

  // DMA source mapping: lane i deposits at slot + i*16 (HW-fixed). We want LDS
  // position (row r=i>>3, chunk j=i&7) to hold global chunk c=(j-r)&7 -> rotated
  // frag reads hit all 8 bank groups evenly. Same 128B lines, permuted lanes.
  const int rr = lane >> 3;              // row within 8-row block
  const int cc = lane & 7;               // dest chunk
  const int gchunk = (cc - rr) & 7;      // source chunk within the 128B k-slice

  const int n0base = (blockIdx.x * NWAVES + wave) * 8;   // t-rows for it=0
  const char* g1 = (const char*)h1 + (size_t)(n0base + rr) * 1024 + gchunk * 16;
  const char* g2 = (const char*)h2 + (size_t)(n0base + rr) * 1024 + gchunk * 16;

  // A-frag LDS read offsets (row r=l15&7, block=l15>>3, chunks 2q,2q+1 rotated):
  const int r7 = l15 & 7;
  const int fragbase = (l15 >> 3) * 1024 + r7 * 128;
  const int j1 = ((2 * q + r7) & 7) * 16;
  const int j2 = ((2 * q + 1 + r7) & 7) * 16;

  // Prologue: stage steps 0 and 1.
  {
    dma16(g1, aslot);              dma16(g2, aslot + 1024);
    dma16(g1 + 128, aslot + 2048); dma16(g2 + 128, aslot + 2048 + 1024);
  }

  #pragma unroll
  for (int it = 0; it < ITERS; ++it) {
    f32x4 acc[8];
    #pragma unroll
    for (int lt = 0; lt < 8; ++lt) acc[lt] = (f32x4){0.f, 0.f, 0.f, 0.f};

    #pragma unroll
    for (int ks = 0; ks < 8; ++ks) {
      const int s = it * 8 + ks;
      if (s + 2 < TOT) {                 // stage step s+2 (compile-time predicate)
        const int s2 = s + 2;
        const size_t off = (size_t)(s2 >> 3) * ITSTR + (s2 & 7) * 128;
        char* dst = aslot + (s2 % 3) * 2048;
        dma16(g1 + off, dst);
        dma16(g2 + off, dst + 1024);
      }
      // wait for step s's two DMAs (FIFO: >=4 newer ops always issued after them,
      // except at the tail where fewer prefetches exist)
      if (s + 2 < TOT)      asm volatile("s_waitcnt vmcnt(4)" ::: "memory");
      else if (s + 1 < TOT) asm volatile("s_waitcnt vmcnt(2)" ::: "memory");
      else                  asm volatile("s_waitcnt vmcnt(0)" ::: "memory");

      const char* ab = aslot + (s % 3) * 2048 + fragbase;
      float4 fa = *(const float4*)(ab + j1);   // k = q*8 .. q*8+3
      float4 fb = *(const float4*)(ab + j2);   // k = q*8+4 .. q*8+7
      ABFrag a;
      a.u[0] = f2bf(fa.x); a.u[1] = f2bf(fa.y); a.u[2] = f2bf(fa.z); a.u[3] = f2bf(fa.w);
      a.u[4] = f2bf(fb.x); a.u[5] = f2bf(fb.y); a.u[6] = f2bf(fb.z); a.u[7] = f2bf(fb.w);
      #pragma unroll
      for (int lt = 0; lt < 8; ++lt) {
        const int l = (lt << 4) + l15;
        bf16x8 bfr = *(const bf16x8*)&vlds[(l << 8) + (((4 * ks + q + l) & 31) << 3)];
        acc[lt] = __builtin_amdgcn_mfma_f32_16x16x32_bf16(a.v, bfr, acc[lt], 0, 0, 0);
      }
    }

    // Epilogue: s_p[r] = sum_l w[l]*tanh(temp); D: col L=16*lt+l15, row m=q*4+r.
    // Rows m=0..7 are stream-0 (h1) scores, m=8..15 stream-1 (h2), same t-rows.
    float s_p[4] = {0.f, 0.f, 0.f, 0.f};
    #pragma unroll
    for (int lt = 0; lt < 8; ++lt) {
      #pragma unroll
      for (int r = 0; r < 4; ++r)
        s_p[r] += wreg[lt] * fast_tanh(acc[lt][r]);
    }
    #pragma unroll
    for (int r = 0; r < 4; ++r) {
      #pragma unroll
      for (int off = 1; off < 16; off <<= 1)
        s_p[r] += __shfl_xor(s_p[r], off);
    }
    const int r = l15 & 3;
    float sel = (r == 0) ? s_p[0] : (r == 1) ? s_p[1] : (r == 2) ? s_p[2] : s_p[3];
    float oth = __shfl_xor(sel, 32);     // partner quad carries the other stream
    if (q < 2 && l15 < 4) {
      int n = n0base + it * ROWS_PER_IT + q * 4 + l15;
      int b = n >> 12, t = n & 4095;
      float e  = __builtin_amdgcn_exp2f(-1.442695041f * (sel - oth));
      float a0 = __builtin_amdgcn_rcpf(1.0f + e);
      out[b * 8192 + t]        = a0;
      out[b * 8192 + 4096 + t] = 1.0f - a0;
    }
  }
}

extern "C" void kernel_launch(void* const* d_in, const int* in_sizes, int n_in,
                              void* d_out, int out_size, void* d_ws, size_t ws_size,
                              hipStream_t stream) {
  const float* h1 = (const float*)d_in[0];   // (32,4096,256) fp32
  const float* h2 = (const float*)d_in[1];   // (32,4096,256) fp32
  const float* w  = (const float*)d_in[2];   // (1,128) fp32
  const float* v  = (const float*)d_in[3];   // (128,256) fp32
  float* out = (float*)d_out;                // (32,2,4096) fp32

  hipFuncSetAttribute((const void*)topo_attn_kernel,
                      hipFuncAttributeMaxDynamicSharedMemorySize, SMEMSZ);
  topo_attn_kernel<<<NWG, 1024, SMEMSZ, stream>>>(h1, h2, w, v, out);
}

// Round 6
// 287.664 us; speedup vs baseline: 1.0115x; 1.0115x over previous
//
#include <hip/hip_runtime.h>

// Topo_Attention: out[b,c,t] = softmax_c( sum_l w[l]*tanh(sum_m v[l,m]*h_c[b,t,m]) )
// B=32, T=4096, M=256, L=128.  bf16 MFMA GEMM; memory-bound.
// R10: DRAM-page-locality theory. R4/R8/R9 all plateau at ~2.6 TB/s combined
//     (HBM+L3) with every pipe idle: each 1KB row was read as 8x128B touches
//     1.6us apart with 16K streams interleaving -> every touch is a fresh DRAM
//     row activation (~1/3 DRAM efficiency; m13 streaming ubench = 6.3 TB/s).
//     Fix: A never needed LDS (zero cross-lane reuse). Per it, burst-issue all
//     16 loads (16 rows x full 1KB) back-to-back into a 128-VGPR double buffer
//     -> one page activation per KB. Plain C loads (compiler emits exact
//     per-use vmcnt); sched_barrier(0) pins burst placement + per-ks regions.
//     launch_bounds(512,2) is the only allocator-clean config (R4:72, R8:96
//     regs vs 64+spill for (512,4)/(1024,1)/waves_per_eu). LDS = V only 64KB.
//     Numerics bit-identical to R1-R9.

typedef unsigned short u16;
typedef unsigned int   u32;
typedef __bf16 bf16x8 __attribute__((ext_vector_type(8)));
typedef float  f32x4  __attribute__((ext_vector_type(4)));

union ABFrag { bf16x8 v; u16 u[8]; uint4 q4; };

__device__ __forceinline__ u16 f2bf(float f) {
  // round-to-nearest-even fp32 -> bf16 (finite inputs; no NaN path)
  u32 u = __float_as_uint(f);
  u += 0x7fffu + ((u >> 16) & 1u);
  return (u16)(u >> 16);
}

__device__ __forceinline__ float fast_tanh(float x) {
  float t = __builtin_amdgcn_exp2f(2.885390082f * x);
  return 1.0f - 2.0f * __builtin_amdgcn_rcpf(t + 1.0f);
}

#define NWG    256
#define ITERS  8
#define ROWS_PER_IT (NWG * 64)          // 16384 t-rows per iter device-wide
#define SMEMSZ 65536                    // V bf16 only

__global__ __launch_bounds__(512, 2) void topo_attn_kernel(
    const float* __restrict__ h1, const float* __restrict__ h2,
    const float* __restrict__ w,  const float* __restrict__ vfp,
    float* __restrict__ out) {
  extern __shared__ __align__(16) char smem[];
  u16* vlds = (u16*)smem;               // V bf16, R1 rotate layout (64KB)

  const int tid = threadIdx.x;

  { // one-time: convert V fp32 -> bf16 into LDS, rotate swizzle (chunk g -> (g+l)&31)
    const float4* src = (const float4*)vfp;
    #pragma unroll
    for (int k = 0; k < 8; ++k) {
      int gi = k * 512 + tid;            // 8-elem group index, 0..4095
      float4 f0 = src[gi * 2];
      float4 f1 = src[gi * 2 + 1];
      ABFrag t;
      t.u[0] = f2bf(f0.x); t.u[1] = f2bf(f0.y); t.u[2] = f2bf(f0.z); t.u[3] = f2bf(f0.w);
      t.u[4] = f2bf(f1.x); t.u[5] = f2bf(f1.y); t.u[6] = f2bf(f1.z); t.u[7] = f2bf(f1.w);
      int l = gi >> 5;                   // 0..127
      int g = gi & 31;                   // 0..31
      *(uint4*)&vlds[(l << 8) + (((g + l) & 31) << 3)] = t.q4;
    }
  }
  __syncthreads();                       // only barrier in the kernel

  const int lane = tid & 63;
  const int wave = tid >> 6;             // 0..7
  const int l15  = lane & 15;            // MFMA A-row / D-col lane index
  const int q    = lane >> 4;            // quad: A k = q*8+j ; D row = q*4+reg

  float wreg[8];
  #pragma unroll
  for (int lt = 0; lt < 8; ++lt) wreg[lt] = w[lt * 16 + l15];

  const int n0base = (blockIdx.x * 8 + wave) * 8;   // t-rows for it=0

  // Per-lane A source: A-row l15 (0-7 = h1 rows n0+l15, 8-15 = h2 rows n0+l15-8),
  // k-offset q*8 floats. Lane fragment = 32B contiguous; the 16-load burst for
  // one it covers 16 rows x full 1KB, requested within ~100 cycles -> one DRAM
  // page activation per KB (vs 8 touches 1.6us apart in R4).
  const float* ap = (l15 < 8)
      ? h1 + (size_t)(n0base + l15) * 256
      : h2 + (size_t)(n0base + l15 - 8) * 256;
  ap += q * 8;

  #define LDA(it_, ks_, x, y) do {                                               \
    const float* _p = ap + (size_t)(it_) * ((size_t)ROWS_PER_IT * 256)           \
                         + (ks_) * 32;                                           \
    (x) = *(const float4*)_p; (y) = *(const float4*)(_p + 4); } while (0)

  // Double-buffered full-it prefetch: 2 x 8 ks x 2 float4 = 128 VGPRs.
  float4 pf[2][8][2];
  #pragma unroll
  for (int ks = 0; ks < 8; ++ks) LDA(0, ks, pf[0][ks][0], pf[0][ks][1]);

  #pragma unroll
  for (int it = 0; it < ITERS; ++it) {
    // Burst-issue ALL of it+1's loads back-to-back (temporal page locality),
    // then fence so the scheduler can neither sink the burst nor hoist
    // converts above it.
    if (it + 1 < ITERS) {
      #pragma unroll
      for (int ks = 0; ks < 8; ++ks)
        LDA(it + 1, ks, pf[(it + 1) & 1][ks][0], pf[(it + 1) & 1][ks][1]);
    }
    __builtin_amdgcn_sched_barrier(0);

    f32x4 acc[8];
    #pragma unroll
    for (int lt = 0; lt < 8; ++lt) acc[lt] = (f32x4){0.f, 0.f, 0.f, 0.f};

    #pragma unroll
    for (int ks = 0; ks < 8; ++ks) {
      __builtin_amdgcn_sched_barrier(0);   // per-step region: pins liveness decay
      const float4 cfa = pf[it & 1][ks][0];
      const float4 cfb = pf[it & 1][ks][1];
      ABFrag a;                            // fp32 -> bf16 in-register
      a.u[0] = f2bf(cfa.x); a.u[1] = f2bf(cfa.y); a.u[2] = f2bf(cfa.z); a.u[3] = f2bf(cfa.w);
      a.u[4] = f2bf(cfb.x); a.u[5] = f2bf(cfb.y); a.u[6] = f2bf(cfb.z); a.u[7] = f2bf(cfb.w);

      #pragma unroll
      for (int lt = 0; lt < 8; ++lt) {
        const int l = (lt << 4) + l15;
        bf16x8 bfr = *(const bf16x8*)&vlds[(l << 8) + (((4 * ks + q + l) & 31) << 3)];
        acc[lt] = __builtin_amdgcn_mfma_f32_16x16x32_bf16(a.v, bfr, acc[lt], 0, 0, 0);
      }
    }

    // Epilogue: s_p[r] = sum_l w[l]*tanh(temp); D: col L=16*lt+l15, row m=q*4+r.
    // Rows m=0..7 are stream-0 (h1) scores, m=8..15 stream-1 (h2), same t-rows.
    float s_p[4] = {0.f, 0.f, 0.f, 0.f};
    #pragma unroll
    for (int lt = 0; lt < 8; ++lt) {
      #pragma unroll
      for (int r = 0; r < 4; ++r)
        s_p[r] += wreg[lt] * fast_tanh(acc[lt][r]);
    }
    #pragma unroll
    for (int r = 0; r < 4; ++r) {
      #pragma unroll
      for (int off = 1; off < 16; off <<= 1)
        s_p[r] += __shfl_xor(s_p[r], off);
    }
    const int r = l15 & 3;
    float sel = (r == 0) ? s_p[0] : (r == 1) ? s_p[1] : (r == 2) ? s_p[2] : s_p[3];
    float oth = __shfl_xor(sel, 32);     // partner quad carries the other stream
    if (q < 2 && l15 < 4) {
      int n = n0base + it * ROWS_PER_IT + q * 4 + l15;
      int b = n >> 12, t = n & 4095;
      float e  = __builtin_amdgcn_exp2f(-1.442695041f * (sel - oth));
      float a0 = __builtin_amdgcn_rcpf(1.0f + e);
      out[b * 8192 + t]        = a0;
      out[b * 8192 + 4096 + t] = 1.0f - a0;
    }
  }
}

extern "C" void kernel_launch(void* const* d_in, const int* in_sizes, int n_in,
                              void* d_out, int out_size, void* d_ws, size_t ws_size,
                              hipStream_t stream) {
  const float* h1 = (const float*)d_in[0];   // (32,4096,256) fp32
  const float* h2 = (const float*)d_in[1];   // (32,4096,256) fp32
  const float* w  = (const float*)d_in[2];   // (1,128) fp32
  const float* v  = (const float*)d_in[3];   // (128,256) fp32
  float* out = (float*)d_out;                // (32,2,4096) fp32

  hipFuncSetAttribute((const void*)topo_attn_kernel,
                      hipFuncAttributeMaxDynamicSharedMemorySize, SMEMSZ);
  topo_attn_kernel<<<NWG, 512, SMEMSZ, stream>>>(h1, h2, w, v, out);
}